// Round 1
// 1952.622 us; speedup vs baseline: 1.0856x; 1.0856x over previous
//
#include <hip/hip_runtime.h>

#define V_NODES 100000
#define NTOT (4 * V_NODES)      // concatenated per-relation counter space
#define SCAN_CHUNK 4096         // elements per scan block (256 thr x 16)
#define NBLK ((NTOT + SCAN_CHUNK - 1) / SCAN_CHUNK)  // 98
#define SCORE_BLOCKS (V_NODES / 4)   // 25000
#define PULL_BPR (V_NODES / 4)       // blocks per relation in fused pull

__device__ __forceinline__ float waveAllSum(float v) {
#pragma unroll
    for (int o = 32; o > 0; o >>= 1) v += __shfl_xor(v, o, 64);
    return v;
}

// ---------- phase 1: per-node attention scores (stores exp(e)) + fused histogram ----------
// blocks [0, SCORE_BLOCKS): score path (VALU-bound). blocks after: histogram (atomic-bound).
// Fusing lets the two occupy the GPU concurrently in one launch.
__global__ __launch_bounds__(256) void phase1_kernel(
    const float* __restrict__ lN, const float* __restrict__ gN,
    const float* __restrict__ lW1, const float* __restrict__ lw2,
    const float* __restrict__ gW1, const float* __restrict__ gw2,
    float* __restrict__ eL, float* __restrict__ eG,
    const int* __restrict__ local_dst, int EL,
    const int* __restrict__ ng_dst, int ENG,
    const int* __restrict__ int_dst, int EI,
    const int* __restrict__ sim_dst, int ES,
    int* __restrict__ counts)
{
    if (blockIdx.x < SCORE_BLOCKS) {
        __shared__ float sLW1[4096];
        __shared__ float sGW1[4096];
        __shared__ float sLw2[64];
        __shared__ float sGw2[64];
        for (int i = threadIdx.x; i < 4096; i += 256) { sLW1[i] = lW1[i]; sGW1[i] = gW1[i]; }
        if (threadIdx.x < 64) { sLw2[threadIdx.x] = lw2[threadIdx.x]; sGw2[threadIdx.x] = gw2[threadIdx.x]; }
        __syncthreads();
        int wave = threadIdx.x >> 6, lane = threadIdx.x & 63;
        int v = blockIdx.x * 4 + wave;
        float nl = lN[v * 64 + lane];
        float ng = gN[v * 64 + lane];
        float yl = 0.f, yg = 0.f;
#pragma unroll
        for (int k = 0; k < 64; k++) {
            float al = __shfl(nl, k, 64), ag = __shfl(ng, k, 64);
            yl += al * sLW1[k * 64 + lane];
            yg += ag * sGW1[k * 64 + lane];
        }
        float el = waveAllSum(tanhf(yl) * sLw2[lane]);
        float eg = waveAllSum(tanhf(yg) * sGw2[lane]);
        // store exp(e) directly: pulls then need only a gather, no expf per edge
        if (lane == 0) { eL[v] = __expf(el); eG[v] = __expf(eg); }
    } else {
        long long i = (long long)(blockIdx.x - SCORE_BLOCKS) * 256 + threadIdx.x;
        long long t1 = EL, t2 = t1 + ENG, t3 = t2 + EI, t4 = t3 + ES;
        if (i >= t4) return;
        int d, slot;
        if (i < t1)      { d = local_dst[i];      slot = 0; }
        else if (i < t2) { d = ng_dst[i - t1];    slot = 1; }
        else if (i < t3) { d = int_dst[i - t2];   slot = 2; }
        else             { d = sim_dst[i - t3];   slot = 3; }
        atomicAdd(&counts[slot * V_NODES + d], 1);
    }
}

// ---------- CSR scan (unchanged) ----------
__global__ __launch_bounds__(256) void scan_partial(const int* __restrict__ counts, int* __restrict__ blockSums) {
    __shared__ int sdata[256];
    int base = blockIdx.x * SCAN_CHUNK + threadIdx.x * 16;
    int s = 0;
#pragma unroll
    for (int i = 0; i < 16; i++) { int idx = base + i; if (idx < NTOT) s += counts[idx]; }
    sdata[threadIdx.x] = s;
    __syncthreads();
    for (int o = 128; o > 0; o >>= 1) {
        if (threadIdx.x < o) sdata[threadIdx.x] += sdata[threadIdx.x + o];
        __syncthreads();
    }
    if (threadIdx.x == 0) blockSums[blockIdx.x] = sdata[0];
}

__global__ void scan_blocksums(int* __restrict__ blockSums) {
    __shared__ int s[128];
    int t = threadIdx.x;
    s[t] = (t < NBLK) ? blockSums[t] : 0;
    __syncthreads();
    if (t == 0) {
        int run = 0;
        for (int i = 0; i < NBLK; i++) { int c = s[i]; s[i] = run; run += c; }
    }
    __syncthreads();
    if (t < NBLK) blockSums[t] = s[t];
}

__global__ __launch_bounds__(256) void scan_final(
    const int* __restrict__ counts, const int* __restrict__ blockSums,
    int* __restrict__ off, int* __restrict__ cursor)
{
    __shared__ int pref[256];
    int t = threadIdx.x;
    int base = blockIdx.x * SCAN_CHUNK + t * 16;
    int vals[16];
    int s = 0;
#pragma unroll
    for (int i = 0; i < 16; i++) {
        int idx = base + i;
        int c = (idx < NTOT) ? counts[idx] : 0;
        vals[i] = s; s += c;
    }
    pref[t] = s;
    __syncthreads();
    for (int o = 1; o < 256; o <<= 1) {
        int v = (t >= o) ? pref[t - o] : 0;
        __syncthreads();
        pref[t] += v;
        __syncthreads();
    }
    int thOff = pref[t] - s + blockSums[blockIdx.x];
#pragma unroll
    for (int i = 0; i < 16; i++) {
        int idx = base + i;
        if (idx < NTOT) { int o2 = thOff + vals[i]; off[idx] = o2; cursor[idx] = o2; }
    }
}

// ---------- fused bucket fill (all 4 relations, one launch) ----------
// payload: src node for GAT relations; global edge-row id for mean relations.
__global__ __launch_bounds__(256) void fill_all(
    const int* __restrict__ local_dst, const int* __restrict__ local_src, int EL,
    const int* __restrict__ ng_dst, const int* __restrict__ ng_src, int ENG,
    const int* __restrict__ int_dst, int EI,
    const int* __restrict__ sim_dst, int ES,
    int* __restrict__ cursor, int* __restrict__ bucket)
{
    long long i = (long long)blockIdx.x * 256 + threadIdx.x;
    long long t1 = EL, t2 = t1 + ENG, t3 = t2 + EI, t4 = t3 + ES;
    if (i >= t4) return;
    int d, slot, payload;
    if (i < t1)      { d = local_dst[i];                slot = 0; payload = local_src[i]; }
    else if (i < t2) { long long k = i - t1; d = ng_dst[k]; slot = 1; payload = ng_src[k]; }
    else if (i < t3) { long long k = i - t2; d = int_dst[k]; slot = 2; payload = (int)k; }
    else             { long long k = i - t3; d = sim_dst[k]; slot = 3; payload = (int)(k + EI); }
    int pos = atomicAdd(&cursor[slot * V_NODES + d], 1);
    bucket[pos] = payload;
}

// ---------- fused pull: 4 relations, 4-edges-per-iteration lane-group layout ----------
// Wave layout: 4 lane-groups of 16; group g handles edge j+g, lane (l&15) handles
// features [(l&15)*4 .. +3] via one float4. One global_load_dwordx4 instruction
// covers 4 edges' rows; 8-edge manual unroll keeps 2 loads in flight.
// GAT relations: w = exp(e[src]) (pre-exponentiated). Mean relations: w = 1.
__global__ __launch_bounds__(256) void pull_all(
    const int* __restrict__ off, const int* __restrict__ endp, const int* __restrict__ bucket,
    const float* __restrict__ lN, const float* __restrict__ gN, const float* __restrict__ edge_E,
    const float* __restrict__ eL, const float* __restrict__ eG,
    float* __restrict__ out, float* __restrict__ Np,
    float* __restrict__ YI, float* __restrict__ YS)
{
    int rel = blockIdx.x / PULL_BPR;
    int vb = blockIdx.x % PULL_BPR;
    int wave = threadIdx.x >> 6, lane = threadIdx.x & 63;
    int v = vb * 4 + wave;

    const float* base; const float* eArr; float* dst; int stride;
    if (rel == 0)      { base = lN;     eArr = eL;      dst = out; stride = 128; }
    else if (rel == 1) { base = gN;     eArr = eG;      dst = Np;  stride = 64; }
    else if (rel == 2) { base = edge_E; eArr = nullptr; dst = YI;  stride = 64; }
    else               { base = edge_E; eArr = nullptr; dst = YS;  stride = 64; }

    int start = off[rel * V_NODES + v], end = endp[rel * V_NODES + v];
    int g = lane >> 4, f4 = (lane & 15) * 4;
    float4 acc = {0.f, 0.f, 0.f, 0.f};
    float den = 0.f;

    for (int e0 = start; e0 < end; e0 += 64) {
        int n = min(64, end - e0);
        int idx = (lane < n) ? bucket[e0 + lane] : 0;
        float w = (lane < n) ? (eArr ? eArr[idx] : 1.f) : 0.f;
        int j = 0;
        // main: 8 edges per iteration, 2 independent dwordx4 loads in flight
        for (; j + 8 <= n; j += 8) {
            int j0 = j + g, j1 = j + 4 + g;
            int s0 = __shfl(idx, j0, 64);
            int s1 = __shfl(idx, j1, 64);
            float w0 = __shfl(w, j0, 64);
            float w1 = __shfl(w, j1, 64);
            float4 a = *(const float4*)(base + (long long)s0 * 64 + f4);
            float4 b = *(const float4*)(base + (long long)s1 * 64 + f4);
            acc.x += w0 * a.x + w1 * b.x;
            acc.y += w0 * a.y + w1 * b.y;
            acc.z += w0 * a.z + w1 * b.z;
            acc.w += w0 * a.w + w1 * b.w;
            den += w0 + w1;
        }
        // tail: 4 edges per iteration, masked
        for (; j < n; j += 4) {
            int jj = j + g;
            bool ok = jj < n;
            int jc = ok ? jj : 0;
            int s = __shfl(idx, jc, 64);
            float wv = __shfl(w, jc, 64);
            float wj = ok ? wv : 0.f;
            float4 a = *(const float4*)(base + (long long)s * 64 + f4);
            acc.x += wj * a.x; acc.y += wj * a.y;
            acc.z += wj * a.z; acc.w += wj * a.w;
            den += wj;
        }
    }

    // reduce the 4 lane-groups (partial sums per feature-quad live in lanes l, l+16, l+32, l+48)
#pragma unroll
    for (int o = 16; o < 64; o <<= 1) {
        acc.x += __shfl_xor(acc.x, o, 64);
        acc.y += __shfl_xor(acc.y, o, 64);
        acc.z += __shfl_xor(acc.z, o, 64);
        acc.w += __shfl_xor(acc.w, o, 64);
        den   += __shfl_xor(den, o, 64);
    }
    den = den > 0.f ? den : 1.f;
    float inv = 1.f / den;
    if (g == 0) {
        float4 r = {acc.x * inv, acc.y * inv, acc.z * inv, acc.w * inv};
        *(float4*)(dst + (long long)v * stride + f4) = r;
    }
}

// ---------- epilogue: 2-way edge attention, project, combine ----------
__global__ __launch_bounds__(256) void finalize_kernel(
    const float* __restrict__ Np, const float* __restrict__ YIb, const float* __restrict__ YSb,
    const float* __restrict__ eW1, const float* __restrict__ ew2,
    const float* __restrict__ eW3, const float* __restrict__ Ws,
    float* __restrict__ out)
{
    __shared__ float sW1[4096];
    __shared__ float sW3[4096];
    __shared__ float sw2[64];
    for (int i = threadIdx.x; i < 4096; i += 256) { sW1[i] = eW1[i]; sW3[i] = eW3[i]; }
    if (threadIdx.x < 64) sw2[threadIdx.x] = ew2[threadIdx.x];
    __syncthreads();
    int wave = threadIdx.x >> 6, lane = threadIdx.x & 63;
    int v = blockIdx.x * 4 + wave;
    if (v >= V_NODES) return;

    float Npv = Np[v * 64 + lane];
    float yi = YIb[v * 64 + lane];
    float ys = YSb[v * 64 + lane];

    float ti = 0.f, ts = 0.f;
#pragma unroll
    for (int k = 0; k < 64; k++) {
        float w = sW1[k * 64 + lane];
        ti += __shfl(yi, k, 64) * w;
        ts += __shfl(ys, k, 64) * w;
    }
    float eI = waveAllSum(tanhf(ti) * sw2[lane]);
    float eS = waveAllSum(tanhf(ts) * sw2[lane]);
    float m = fmaxf(eI, eS);
    float a0 = __expf(eI - m), a1 = __expf(eS - m);
    float inv = 1.f / (a0 + a1);
    a0 *= inv; a1 *= inv;
    float oy = a0 * yi + a1 * ys;

    float fg = 0.f;
#pragma unroll
    for (int k = 0; k < 64; k++) fg += __shfl(oy, k, 64) * sW3[k * 64 + lane];

    float S = Ws[v * 64 + lane] * fg + Npv;
    out[(long long)v * 128 + 64 + lane] = S;
}

extern "C" void kernel_launch(void* const* d_in, const int* in_sizes, int n_in,
                              void* d_out, int out_size, void* d_ws, size_t ws_size,
                              hipStream_t stream) {
    const float* local_N = (const float*)d_in[0];
    const float* global_N = (const float*)d_in[1];
    const float* edge_E = (const float*)d_in[2];
    const float* Ws = (const float*)d_in[3];
    const float* lW1 = (const float*)d_in[4];
    const float* lw2 = (const float*)d_in[5];
    const float* gW1 = (const float*)d_in[6];
    const float* gw2 = (const float*)d_in[7];
    const float* eW1 = (const float*)d_in[8];
    const float* ew2 = (const float*)d_in[9];
    const float* eW3 = (const float*)d_in[10];
    const int* ng_src = (const int*)d_in[11];
    const int* ng_dst = (const int*)d_in[12];
    const int* local_src = (const int*)d_in[13];
    const int* local_dst = (const int*)d_in[14];
    const int* int_dst = (const int*)d_in[16];
    const int* sim_dst = (const int*)d_in[18];
    float* out = (float*)d_out;

    const int E_NG = in_sizes[11];
    const int E_LOCAL = in_sizes[13];
    const int E_INT = in_sizes[15];
    const int E_SIM = in_sizes[17];
    const int E_ALL = E_LOCAL + E_NG + E_INT + E_SIM;
    const long long V = V_NODES;

    // ---- workspace layout ----
    float* fw = (float*)d_ws;
    float* eLp = fw;                 // V   (holds exp of local scores)
    float* eGp = eLp + V;            // V   (holds exp of global scores)
    float* Np  = eGp + V;            // V*64
    float* YI  = Np + V * 64;        // V*64
    float* YS  = YI + V * 64;        // V*64
    int* iw = (int*)(YS + V * 64);
    int* counts   = iw;              // NTOT
    int* offsets  = counts + NTOT;   // NTOT
    int* cursor   = offsets + NTOT;  // NTOT
    int* blockSums = cursor + NTOT;  // 128
    int* bucket   = blockSums + 128; // E_ALL

    hipMemsetAsync(counts, 0, (size_t)NTOT * sizeof(int), stream);

    const int histBlocks = (E_ALL + 255) / 256;
    phase1_kernel<<<SCORE_BLOCKS + histBlocks, 256, 0, stream>>>(
        local_N, global_N, lW1, lw2, gW1, gw2, eLp, eGp,
        local_dst, E_LOCAL, ng_dst, E_NG, int_dst, E_INT, sim_dst, E_SIM, counts);

    scan_partial<<<NBLK, 256, 0, stream>>>(counts, blockSums);
    scan_blocksums<<<1, 128, 0, stream>>>(blockSums);
    scan_final<<<NBLK, 256, 0, stream>>>(counts, blockSums, offsets, cursor);

    fill_all<<<histBlocks, 256, 0, stream>>>(
        local_dst, local_src, E_LOCAL, ng_dst, ng_src, E_NG,
        int_dst, E_INT, sim_dst, E_SIM, cursor, bucket);

    // fused pulls: rel0=local GAT (writes H[:, :64]), rel1=global GAT (Np),
    // rel2=INT mean (YI), rel3=SIM mean (YS); cursor[x]==end after fill
    pull_all<<<4 * PULL_BPR, 256, 0, stream>>>(
        offsets, cursor, bucket, local_N, global_N, edge_E, eLp, eGp,
        out, Np, YI, YS);

    finalize_kernel<<<SCORE_BLOCKS, 256, 0, stream>>>(Np, YI, YS, eW1, ew2, eW3, Ws, out);
}

// Round 2
// 1459.161 us; speedup vs baseline: 1.4527x; 1.3382x over previous
//
#include <hip/hip_runtime.h>

#define V_NODES 100000
#define NTOT (4 * V_NODES)
#define BINW 256                                  // nodes per bin (dst >> 8)
#define NBIN_REL ((V_NODES + BINW - 1) / BINW)    // 391
#define NBINS_TOT (4 * NBIN_REL)                  // 1564
#define SCORE_BLOCKS (V_NODES / 4)                // 25000
#define PULL_BPR (V_NODES / 4)
#define HIST_CHUNK 8192                           // edges per block in hist/scatter passes
#define HIST_ITERS (HIST_CHUNK / 256)             // 32

__device__ __forceinline__ float waveAllSum(float v) {
#pragma unroll
    for (int o = 32; o > 0; o >>= 1) v += __shfl_xor(v, o, 64);
    return v;
}

// ---------- phase 1: per-node attention scores (stores exp(e)) + fused BIN histogram ----------
// blocks [0, SCORE_BLOCKS): score path (VALU-bound). blocks after: bin histogram
// (LDS-aggregated, one flush atomic per touched bin per block).
__global__ __launch_bounds__(256) void phase1_kernel(
    const float* __restrict__ lN, const float* __restrict__ gN,
    const float* __restrict__ lW1, const float* __restrict__ lw2,
    const float* __restrict__ gW1, const float* __restrict__ gw2,
    float* __restrict__ eL, float* __restrict__ eG,
    const int* __restrict__ local_dst, int EL,
    const int* __restrict__ ng_dst, int ENG,
    const int* __restrict__ int_dst, int EI,
    const int* __restrict__ sim_dst, int ES,
    int* __restrict__ binCnt)
{
    __shared__ float sLW1[4096];
    __shared__ float sGW1[4096];
    __shared__ float sLw2[64];
    __shared__ float sGw2[64];
    __shared__ int bh[NBINS_TOT];

    if (blockIdx.x < SCORE_BLOCKS) {
        for (int i = threadIdx.x; i < 4096; i += 256) { sLW1[i] = lW1[i]; sGW1[i] = gW1[i]; }
        if (threadIdx.x < 64) { sLw2[threadIdx.x] = lw2[threadIdx.x]; sGw2[threadIdx.x] = gw2[threadIdx.x]; }
        __syncthreads();
        int wave = threadIdx.x >> 6, lane = threadIdx.x & 63;
        int v = blockIdx.x * 4 + wave;
        float nl = lN[v * 64 + lane];
        float ng = gN[v * 64 + lane];
        float yl = 0.f, yg = 0.f;
#pragma unroll
        for (int k = 0; k < 64; k++) {
            float al = __shfl(nl, k, 64), ag = __shfl(ng, k, 64);
            yl += al * sLW1[k * 64 + lane];
            yg += ag * sGW1[k * 64 + lane];
        }
        float el = waveAllSum(tanhf(yl) * sLw2[lane]);
        float eg = waveAllSum(tanhf(yg) * sGw2[lane]);
        // store exp(e): pulls then need only a gather, no expf per edge
        if (lane == 0) { eL[v] = __expf(el); eG[v] = __expf(eg); }
    } else {
        for (int b = threadIdx.x; b < NBINS_TOT; b += 256) bh[b] = 0;
        __syncthreads();
        int t1 = EL, t2 = t1 + ENG, t3 = t2 + EI, t4 = t3 + ES;
        int c0 = (blockIdx.x - SCORE_BLOCKS) * HIST_CHUNK;
#pragma unroll
        for (int k = 0; k < HIST_ITERS; k++) {
            int i = c0 + k * 256 + threadIdx.x;
            if (i < t4) {
                int d, rel;
                if (i < t1)      { d = local_dst[i];      rel = 0; }
                else if (i < t2) { d = ng_dst[i - t1];    rel = 1; }
                else if (i < t3) { d = int_dst[i - t2];   rel = 2; }
                else             { d = sim_dst[i - t3];   rel = 3; }
                atomicAdd(&bh[rel * NBIN_REL + (d >> 8)], 1);
            }
        }
        __syncthreads();
        for (int b = threadIdx.x; b < NBINS_TOT; b += 256) {
            int c = bh[b];
            if (c) atomicAdd(&binCnt[b], c);
        }
    }
}

// ---------- tiny scan over 1564 bin counts ----------
__global__ __launch_bounds__(256) void scan_bins(
    const int* __restrict__ binCnt, int* __restrict__ binOff, int* __restrict__ binCursor)
{
    __shared__ int s[256];
    int t = threadIdx.x;
    int vals[7];
    int sum = 0;
#pragma unroll
    for (int k = 0; k < 7; k++) {
        int idx = t * 7 + k;
        int c = (idx < NBINS_TOT) ? binCnt[idx] : 0;
        vals[k] = sum; sum += c;
    }
    s[t] = sum;
    __syncthreads();
    for (int o = 1; o < 256; o <<= 1) {
        int v = (t >= o) ? s[t - o] : 0;
        __syncthreads();
        s[t] += v;
        __syncthreads();
    }
    int base = s[t] - sum;   // exclusive over threads
#pragma unroll
    for (int k = 0; k < 7; k++) {
        int idx = t * 7 + k;
        if (idx < NBINS_TOT) { int o2 = base + vals[k]; binOff[idx] = o2; binCursor[idx] = o2; }
    }
    if (t == 255) binOff[NBINS_TOT] = s[255];
}

// ---------- staged scatter: edges -> per-bin contiguous staging (packed dstLocal|payload) ----------
__global__ __launch_bounds__(256) void scatter_stage(
    const int* __restrict__ local_dst, const int* __restrict__ local_src, int EL,
    const int* __restrict__ ng_dst, const int* __restrict__ ng_src, int ENG,
    const int* __restrict__ int_dst, int EI,
    const int* __restrict__ sim_dst, int ES,
    int* __restrict__ binCursor, int* __restrict__ staging)
{
    __shared__ int hist[NBINS_TOT];
    __shared__ int cur[NBINS_TOT];
    for (int b = threadIdx.x; b < NBINS_TOT; b += 256) hist[b] = 0;
    __syncthreads();
    int t1 = EL, t2 = t1 + ENG, t3 = t2 + EI, t4 = t3 + ES;
    int c0 = blockIdx.x * HIST_CHUNK;
    // pass 1: per-block bin counts
#pragma unroll
    for (int k = 0; k < HIST_ITERS; k++) {
        int i = c0 + k * 256 + threadIdx.x;
        if (i < t4) {
            int d, rel;
            if (i < t1)      { d = local_dst[i];      rel = 0; }
            else if (i < t2) { d = ng_dst[i - t1];    rel = 1; }
            else if (i < t3) { d = int_dst[i - t2];   rel = 2; }
            else             { d = sim_dst[i - t3];   rel = 3; }
            atomicAdd(&hist[rel * NBIN_REL + (d >> 8)], 1);
        }
    }
    __syncthreads();
    // reserve contiguous ranges per touched bin
    for (int b = threadIdx.x; b < NBINS_TOT; b += 256) {
        int c = hist[b];
        cur[b] = c ? atomicAdd(&binCursor[b], c) : 0;
    }
    __syncthreads();
    // pass 2: write packed edges into reserved slots
#pragma unroll
    for (int k = 0; k < HIST_ITERS; k++) {
        int i = c0 + k * 256 + threadIdx.x;
        if (i < t4) {
            int d, rel, payload;
            if (i < t1)      { d = local_dst[i];                 rel = 0; payload = local_src[i]; }
            else if (i < t2) { int j = i - t1; d = ng_dst[j];    rel = 1; payload = ng_src[j]; }
            else if (i < t3) { int j = i - t2; d = int_dst[j];   rel = 2; payload = j; }
            else             { int j = i - t3; d = sim_dst[j];   rel = 3; payload = j + EI; }
            int gb = rel * NBIN_REL + (d >> 8);
            int pos = atomicAdd(&cur[gb], 1);
            staging[pos] = (int)(((unsigned)(d & 255) << 24) | (unsigned)payload);
        }
    }
}

// ---------- per-bin CSR finalize: exact node offsets + node-grouped bucket ----------
// One block per (relation, bin). The bucket segment (~20KB) is private to this block,
// so scattered writes stay in one XCD's L2 and lines are fully written.
__global__ __launch_bounds__(256) void build_csr(
    const int* __restrict__ staging, const int* __restrict__ binOff,
    int* __restrict__ off, int* __restrict__ endp, int* __restrict__ bucket)
{
    __shared__ int hist[BINW];
    __shared__ int pref[BINW];
    __shared__ int cur[BINW];
    int t = threadIdx.x;
    int gb = blockIdx.x;
    int rel = gb / NBIN_REL, bin = gb % NBIN_REL;
    int segBase = binOff[gb], segEnd = binOff[gb + 1];
    hist[t] = 0;
    __syncthreads();
    for (int i = segBase + t; i < segEnd; i += 256)
        atomicAdd(&hist[(unsigned)staging[i] >> 24], 1);
    __syncthreads();
    int cnt = hist[t];
    pref[t] = cnt;
    __syncthreads();
    for (int o = 1; o < 256; o <<= 1) {
        int v = (t >= o) ? pref[t - o] : 0;
        __syncthreads();
        pref[t] += v;
        __syncthreads();
    }
    int excl = pref[t] - cnt;
    int node0 = bin << 8;
    int nIn = V_NODES - node0; if (nIn > BINW) nIn = BINW;
    if (t < nIn) {
        off[rel * V_NODES + node0 + t] = segBase + excl;
        endp[rel * V_NODES + node0 + t] = segBase + excl + cnt;
    }
    cur[t] = segBase + excl;
    __syncthreads();
    for (int i = segBase + t; i < segEnd; i += 256) {
        int w = staging[i];
        int p = atomicAdd(&cur[(unsigned)w >> 24], 1);
        bucket[p] = w & 0xFFFFFF;
    }
}

// ---------- fused pull: 4 relations, 4-edges-per-iteration lane-group layout ----------
__global__ __launch_bounds__(256) void pull_all(
    const int* __restrict__ off, const int* __restrict__ endp, const int* __restrict__ bucket,
    const float* __restrict__ lN, const float* __restrict__ gN, const float* __restrict__ edge_E,
    const float* __restrict__ eL, const float* __restrict__ eG,
    float* __restrict__ out, float* __restrict__ Np,
    float* __restrict__ YI, float* __restrict__ YS)
{
    int rel = blockIdx.x / PULL_BPR;
    int vb = blockIdx.x % PULL_BPR;
    int wave = threadIdx.x >> 6, lane = threadIdx.x & 63;
    int v = vb * 4 + wave;

    const float* base; const float* eArr; float* dst; int stride;
    if (rel == 0)      { base = lN;     eArr = eL;      dst = out; stride = 128; }
    else if (rel == 1) { base = gN;     eArr = eG;      dst = Np;  stride = 64; }
    else if (rel == 2) { base = edge_E; eArr = nullptr; dst = YI;  stride = 64; }
    else               { base = edge_E; eArr = nullptr; dst = YS;  stride = 64; }

    int start = off[rel * V_NODES + v], end = endp[rel * V_NODES + v];
    int g = lane >> 4, f4 = (lane & 15) * 4;
    float4 acc = {0.f, 0.f, 0.f, 0.f};
    float den = 0.f;

    for (int e0 = start; e0 < end; e0 += 64) {
        int n = min(64, end - e0);
        int idx = (lane < n) ? bucket[e0 + lane] : 0;
        float w = (lane < n) ? (eArr ? eArr[idx] : 1.f) : 0.f;
        int j = 0;
        for (; j + 8 <= n; j += 8) {
            int j0 = j + g, j1 = j + 4 + g;
            int s0 = __shfl(idx, j0, 64);
            int s1 = __shfl(idx, j1, 64);
            float w0 = __shfl(w, j0, 64);
            float w1 = __shfl(w, j1, 64);
            float4 a = *(const float4*)(base + (long long)s0 * 64 + f4);
            float4 b = *(const float4*)(base + (long long)s1 * 64 + f4);
            acc.x += w0 * a.x + w1 * b.x;
            acc.y += w0 * a.y + w1 * b.y;
            acc.z += w0 * a.z + w1 * b.z;
            acc.w += w0 * a.w + w1 * b.w;
            den += w0 + w1;
        }
        for (; j < n; j += 4) {
            int jj = j + g;
            bool ok = jj < n;
            int jc = ok ? jj : 0;
            int s = __shfl(idx, jc, 64);
            float wv = __shfl(w, jc, 64);
            float wj = ok ? wv : 0.f;
            float4 a = *(const float4*)(base + (long long)s * 64 + f4);
            acc.x += wj * a.x; acc.y += wj * a.y;
            acc.z += wj * a.z; acc.w += wj * a.w;
            den += wj;
        }
    }

#pragma unroll
    for (int o = 16; o < 64; o <<= 1) {
        acc.x += __shfl_xor(acc.x, o, 64);
        acc.y += __shfl_xor(acc.y, o, 64);
        acc.z += __shfl_xor(acc.z, o, 64);
        acc.w += __shfl_xor(acc.w, o, 64);
        den   += __shfl_xor(den, o, 64);
    }
    den = den > 0.f ? den : 1.f;
    float inv = 1.f / den;
    if (g == 0) {
        float4 r = {acc.x * inv, acc.y * inv, acc.z * inv, acc.w * inv};
        *(float4*)(dst + (long long)v * stride + f4) = r;
    }
}

// ---------- epilogue: 2-way edge attention, project, combine ----------
__global__ __launch_bounds__(256) void finalize_kernel(
    const float* __restrict__ Np, const float* __restrict__ YIb, const float* __restrict__ YSb,
    const float* __restrict__ eW1, const float* __restrict__ ew2,
    const float* __restrict__ eW3, const float* __restrict__ Ws,
    float* __restrict__ out)
{
    __shared__ float sW1[4096];
    __shared__ float sW3[4096];
    __shared__ float sw2[64];
    for (int i = threadIdx.x; i < 4096; i += 256) { sW1[i] = eW1[i]; sW3[i] = eW3[i]; }
    if (threadIdx.x < 64) sw2[threadIdx.x] = ew2[threadIdx.x];
    __syncthreads();
    int wave = threadIdx.x >> 6, lane = threadIdx.x & 63;
    int v = blockIdx.x * 4 + wave;
    if (v >= V_NODES) return;

    float Npv = Np[v * 64 + lane];
    float yi = YIb[v * 64 + lane];
    float ys = YSb[v * 64 + lane];

    float ti = 0.f, ts = 0.f;
#pragma unroll
    for (int k = 0; k < 64; k++) {
        float w = sW1[k * 64 + lane];
        ti += __shfl(yi, k, 64) * w;
        ts += __shfl(ys, k, 64) * w;
    }
    float eI = waveAllSum(tanhf(ti) * sw2[lane]);
    float eS = waveAllSum(tanhf(ts) * sw2[lane]);
    float m = fmaxf(eI, eS);
    float a0 = __expf(eI - m), a1 = __expf(eS - m);
    float inv = 1.f / (a0 + a1);
    a0 *= inv; a1 *= inv;
    float oy = a0 * yi + a1 * ys;

    float fg = 0.f;
#pragma unroll
    for (int k = 0; k < 64; k++) fg += __shfl(oy, k, 64) * sW3[k * 64 + lane];

    float S = Ws[v * 64 + lane] * fg + Npv;
    out[(long long)v * 128 + 64 + lane] = S;
}

extern "C" void kernel_launch(void* const* d_in, const int* in_sizes, int n_in,
                              void* d_out, int out_size, void* d_ws, size_t ws_size,
                              hipStream_t stream) {
    const float* local_N = (const float*)d_in[0];
    const float* global_N = (const float*)d_in[1];
    const float* edge_E = (const float*)d_in[2];
    const float* Ws = (const float*)d_in[3];
    const float* lW1 = (const float*)d_in[4];
    const float* lw2 = (const float*)d_in[5];
    const float* gW1 = (const float*)d_in[6];
    const float* gw2 = (const float*)d_in[7];
    const float* eW1 = (const float*)d_in[8];
    const float* ew2 = (const float*)d_in[9];
    const float* eW3 = (const float*)d_in[10];
    const int* ng_src = (const int*)d_in[11];
    const int* ng_dst = (const int*)d_in[12];
    const int* local_src = (const int*)d_in[13];
    const int* local_dst = (const int*)d_in[14];
    const int* int_dst = (const int*)d_in[16];
    const int* sim_dst = (const int*)d_in[18];
    float* out = (float*)d_out;

    const int E_NG = in_sizes[11];
    const int E_LOCAL = in_sizes[13];
    const int E_INT = in_sizes[15];
    const int E_SIM = in_sizes[17];
    const int E_ALL = E_LOCAL + E_NG + E_INT + E_SIM;
    const long long V = V_NODES;

    // ---- workspace layout ----
    float* fw = (float*)d_ws;
    float* eLp = fw;                 // V   (exp of local scores)
    float* eGp = eLp + V;            // V   (exp of global scores)
    float* Np  = eGp + V;            // V*64
    float* YI  = Np + V * 64;        // V*64
    float* YS  = YI + V * 64;        // V*64
    int* iw = (int*)(YS + V * 64);
    int* off       = iw;                   // NTOT
    int* endp      = off + NTOT;           // NTOT
    int* binCnt    = endp + NTOT;          // 2048 (NBINS_TOT used)
    int* binOff    = binCnt + 2048;        // 2048 (NBINS_TOT+1 used)
    int* binCursor = binOff + 2048;        // 2048
    int* staging   = binCursor + 2048;     // E_ALL
    int* bucket    = staging + E_ALL;      // E_ALL

    hipMemsetAsync(binCnt, 0, NBINS_TOT * sizeof(int), stream);

    const int histBlocks = (E_ALL + HIST_CHUNK - 1) / HIST_CHUNK;
    phase1_kernel<<<SCORE_BLOCKS + histBlocks, 256, 0, stream>>>(
        local_N, global_N, lW1, lw2, gW1, gw2, eLp, eGp,
        local_dst, E_LOCAL, ng_dst, E_NG, int_dst, E_INT, sim_dst, E_SIM, binCnt);

    scan_bins<<<1, 256, 0, stream>>>(binCnt, binOff, binCursor);

    scatter_stage<<<histBlocks, 256, 0, stream>>>(
        local_dst, local_src, E_LOCAL, ng_dst, ng_src, E_NG,
        int_dst, E_INT, sim_dst, E_SIM, binCursor, staging);

    build_csr<<<NBINS_TOT, 256, 0, stream>>>(staging, binOff, off, endp, bucket);

    pull_all<<<4 * PULL_BPR, 256, 0, stream>>>(
        off, endp, bucket, local_N, global_N, edge_E, eLp, eGp,
        out, Np, YI, YS);

    finalize_kernel<<<SCORE_BLOCKS, 256, 0, stream>>>(Np, YI, YS, eW1, ew2, eW3, Ws, out);
}